// Round 14
// baseline (673.645 us; speedup 1.0000x reference)
//
#include <hip/hip_runtime.h>
#include <hip/hip_fp16.h>
#include <cstdint>

#define GRAPHS 128

using half8 = __attribute__((ext_vector_type(8))) _Float16;
using f32x4 = __attribute__((ext_vector_type(4))) float;

__device__ __forceinline__ float lane_bcast_f(float v, int l) {
  return __int_as_float(__builtin_amdgcn_readlane(__float_as_int(v), l));
}
// async global->LDS DMA, 16B/lane (dwordx4): HW places at wave-uniform base + lane*16
__device__ __forceinline__ void load_lds16(const __half* g, __half* l) {
  __builtin_amdgcn_global_load_lds(
      (const __attribute__((address_space(1))) void*)g,
      (__attribute__((address_space(3))) void*)l, 16, 0, 0);
}
#define WAIT_VM0   __builtin_amdgcn_s_waitcnt(0x0F70)  // vmcnt(0) only
#define WAIT_LGKM0 __builtin_amdgcn_s_waitcnt(0xC07F)  // lgkmcnt(0) only

// ---------------- edge prep: degree -> scan -> scatter (CSR by dst) ----------------

__global__ __launch_bounds__(256) void k_deg(const int* __restrict__ ei, int E, int ET,
                                             int* __restrict__ deg) {
  int e = blockIdx.x * 256 + threadIdx.x;
  if (e >= ET) return;
  int d = (e < E) ? ei[E + e] : (e - E);
  atomicAdd(&deg[d], 1);
}

__global__ __launch_bounds__(256) void k_s1(const int* __restrict__ deg, int N,
                                            int* __restrict__ bsum) {
  int b = blockIdx.x, tid = threadIdx.x;
  int i0 = b * 1024 + tid * 4;
  int s = 0;
#pragma unroll
  for (int e = 0; e < 4; ++e) { int i = i0 + e; if (i < N) s += deg[i]; }
#pragma unroll
  for (int o = 32; o; o >>= 1) s += __shfl_xor(s, o);
  __shared__ int wt[4];
  int lane = tid & 63, wid = tid >> 6;
  if (lane == 0) wt[wid] = s;
  __syncthreads();
  if (tid == 0) bsum[b] = wt[0] + wt[1] + wt[2] + wt[3];
}

__global__ void k_s2(int* bsum, int nb) {
  if (threadIdx.x == 0) {
    int run = 0;
    for (int i = 0; i < nb; ++i) { int t = bsum[i]; bsum[i] = run; run += t; }
  }
}

__global__ __launch_bounds__(256) void k_s3(int* __restrict__ deg_cursor,
                                            const int* __restrict__ bsum,
                                            int* __restrict__ rowptr, int N) {
  int b = blockIdx.x, tid = threadIdx.x;
  int lane = tid & 63, wid = tid >> 6;
  int i0 = b * 1024 + tid * 4;
  int d[4];
#pragma unroll
  for (int e = 0; e < 4; ++e) { int i = i0 + e; d[e] = (i < N) ? deg_cursor[i] : 0; }
  int p0 = d[0], p1 = p0 + d[1], p2 = p1 + d[2], p3 = p2 + d[3];
  int incl = p3;
#pragma unroll
  for (int o = 1; o < 64; o <<= 1) { int u = __shfl_up(incl, o); if (lane >= o) incl += u; }
  __shared__ int wt[4];
  if (lane == 63) wt[wid] = incl;
  __syncthreads();
  int woff = 0;
  for (int w = 0; w < wid; ++w) woff += wt[w];
  int ex = bsum[b] + woff + incl - p3;
  int pre[4] = {0, p0, p1, p2};
#pragma unroll
  for (int e = 0; e < 4; ++e) {
    int i = i0 + e;
    if (i < N) { int st = ex + pre[e]; deg_cursor[i] = st; rowptr[i + 1] = st + d[e]; }
  }
  if (b == 0 && tid == 0) rowptr[0] = 0;
}

__global__ __launch_bounds__(256) void k_scatter(const int* __restrict__ ei, int E, int ET,
                                                 int* __restrict__ cursor,
                                                 int* __restrict__ csrs) {
  int e = blockIdx.x * 256 + threadIdx.x;
  if (e >= ET) return;
  int s, d;
  if (e < E) { s = ei[e]; d = ei[E + e]; } else { s = d = e - E; }
  int pos = atomicAdd(&cursor[d], 1);
  csrs[pos] = s;
}

// ---------------- fp16 conversion / weight transpose ----------------

__global__ __launch_bounds__(256) void k_cvtx(const float* __restrict__ x,
                                              __half* __restrict__ xh, int n4) {
  int i = blockIdx.x * 256 + threadIdx.x;
  if (i >= n4) return;
  float4 v = *(const float4*)&x[(size_t)i * 4];
  __half2 a = __floats2half2_rn(v.x, v.y), b = __floats2half2_rn(v.z, v.w);
  *(__half2*)&xh[(size_t)i * 4] = a;
  *(__half2*)&xh[(size_t)i * 4 + 2] = b;
}

__global__ __launch_bounds__(256) void k_wt(const float* __restrict__ W,
                                            __half* __restrict__ Wt, int K, int NC) {
  int id = blockIdx.x * 256 + threadIdx.x;
  if (id >= K * NC) return;
  int nn = id / K, kk = id % K;
  Wt[(size_t)nn * K + kk] = __float2half(W[(size_t)kk * NC + nn]);
}

// ---------------- MFMA GEMM (fp16 in, fp32 acc, fp16 out) + fused attention dots ------------
// Wave = one 16x16 C tile. A[m=lane&15][k=quad*8+j] frag (contiguous 16B/lane, row-major A);
// B frag from pre-transposed Bt[n][k] (same lane mapping, n=lane&15). C/D: col=lane&15,
// row=quad*4+r (m89/m120-verified). attn dots from fp32 accs, atomicAdd into zeroed aS/aD.

__global__ __launch_bounds__(256) void k_mfma(
    const __half* __restrict__ Ah, const __half* __restrict__ Bth,
    __half* __restrict__ C, const float* __restrict__ attS, const float* __restrict__ attD,
    float* __restrict__ aS, float* __restrict__ aD, int M, int K, int NC, int astr) {
  int w = threadIdx.x >> 6, lane = threadIdx.x & 63;
  int m0 = blockIdx.x * 16;
  int ntile = blockIdx.y * 4 + w;
  int n0 = ntile * 16;
  int col = lane & 15, quad = lane >> 4;
  int head = n0 >> 6;
  const _Float16* A = (const _Float16*)Ah;
  const _Float16* Bt = (const _Float16*)Bth;
  int am = min(m0 + col, M - 1);           // lane&15 = A row (m) for A-frag
  const half8* Ar = (const half8*)(A + (size_t)am * K);
  const half8* Br = (const half8*)(Bt + (size_t)(n0 + col) * K);  // lane&15 = B col (n)
  f32x4 acc = {0.f, 0.f, 0.f, 0.f};
  int ksteps = K >> 5;
#pragma unroll 6
  for (int s = 0; s < ksteps; ++s) {
    half8 a = Ar[s * 4 + quad];
    half8 b = Br[s * 4 + quad];
    acc = __builtin_amdgcn_mfma_f32_16x16x32_f16(a, b, acc, 0, 0, 0);
  }
  float asv = attS[n0 + col], adv = attD[n0 + col];
#pragma unroll
  for (int r = 0; r < 4; ++r) {
    int m = m0 + quad * 4 + r;
    float sv = acc[r] * asv, dv = acc[r] * adv;
#pragma unroll
    for (int o = 1; o < 16; o <<= 1) { sv += __shfl_xor(sv, o); dv += __shfl_xor(dv, o); }
    if (m < M) {
      C[(size_t)m * NC + n0 + col] = __float2half(acc[r]);
      if (col == 0) {
        atomicAdd(&aS[(size_t)m * astr + head], sv);
        atomicAdd(&aD[(size_t)m * astr + head], dv);
      }
    }
  }
}

// ---------------- single-head wave-per-(node,head) softmax + wide-DMA fp16 aggregation -------

template <bool DOELU, bool POOL>
__global__ __launch_bounds__(256) void k_agg1(
    const int* __restrict__ rowptr, const int* __restrict__ csrs,
    const __half* __restrict__ xp, const float* __restrict__ aS, const float* __restrict__ aD,
    const float* __restrict__ bias, __half* __restrict__ out,
    const int* __restrict__ batch, float* __restrict__ pooled, float* __restrict__ gcnt,
    int N, int astr, int rowstr, int outstr) {
  __shared__ __half stage[4][1024];
  int wv = (blockIdx.x * blockDim.x + threadIdx.x) >> 6;
  int lane = threadIdx.x & 63;
  int wid = (threadIdx.x >> 6) & 3;
  if (wv >= N) return;
  __half* st = stage[wid];
  int head = blockIdx.y;
  int coloff = head * 64;
  int n = wv;
  int start = rowptr[n], end = rowptr[n + 1];
  float ad = aD[(size_t)n * astr + head];
  float m = -1e30f, s = 0.f, al = 0.f, cf = 0.f, acc = 0.f;
  int myS = -1;
  int j = start + lane;
  if (j < end) {
    myS = csrs[j];
    float v = aS[(size_t)myS * astr + head] + ad;
    v = v > 0.f ? v : 0.2f * v;
    al = v; m = v; s = 1.f;
  }
  for (int jj = j + 64; jj < end; jj += 64) {  // degree > 64 (rare)
    int sb = csrs[jj];
    float v = aS[(size_t)sb * astr + head] + ad;
    v = v > 0.f ? v : 0.2f * v;
    float M = fmaxf(m, v);
    s = s * __expf(m - M) + __expf(v - M);
    m = M;
  }
  {
    float mm = m, ss = s;
#pragma unroll
    for (int o = 1; o < 64; o <<= 1) {
      float om = __shfl_xor(mm, o), os = __shfl_xor(ss, o);
      float M = fmaxf(mm, om);
      ss = ss * __expf(mm - M) + os * __expf(om - M);
      mm = M;
    }
    m = mm;
    s = 1.0f / fmaxf(ss, 1e-16f);
  }
  if (myS >= 0) cf = __expf(al - m) * s;
  for (int base = start; base < end; base += 64) {
    int cnt = min(64, end - base);
    int sreg; float dd;
    if (base == start) {
      sreg = myS; dd = cf;
    } else {  // degree > 64 spillover (rare)
      int jj = base + lane; sreg = 0; dd = 0.f;
      if (jj < end) {
        sreg = csrs[jj];
        float v = aS[(size_t)sreg * astr + head] + ad;
        v = v > 0.f ? v : 0.2f * v;
        dd = __expf(v - m) * s;
      }
    }
    for (int e = 0; e < cnt; e += 16) {
      WAIT_LGKM0;
#pragma unroll
      for (int k = 0; k < 2; ++k) {
        int ee = min(e + 8 * k + (lane >> 3), cnt - 1);
        int sb = __shfl(sreg, ee);
        const __half* g = xp + (size_t)sb * rowstr + coloff + (lane & 7) * 8;
        load_lds16(g, st + k * 512);
      }
      WAIT_VM0;
#pragma unroll
      for (int u = 0; u < 16; ++u) {
        float c = (e + u < cnt) ? lane_bcast_f(dd, e + u) : 0.f;
        acc = fmaf(c, __half2float(st[(u >> 3) * 512 + (u & 7) * 64 + lane]), acc);
      }
    }
  }
  if (POOL) {
    float val = acc + bias[lane];
    int g = batch[n];
    atomicAdd(&pooled[g * 64 + lane], val);
    if (lane == 0) atomicAdd(&gcnt[g], 1.0f);
  } else {
    float v = acc + bias[coloff + lane];
    if (DOELU) v = v > 0.f ? v : __expf(v) - 1.0f;
    out[(size_t)n * outstr + coloff + lane] = __float2half(v);
  }
}

// ---------------- final: mean + linear ----------------

__global__ __launch_bounds__(64) void k_final(const float* __restrict__ pooled,
                                              const float* __restrict__ gcnt,
                                              const float* __restrict__ lw,
                                              const float* __restrict__ lb,
                                              float* __restrict__ out) {
  int g = blockIdx.x, c = threadIdx.x;
  float inv = 1.0f / fmaxf(gcnt[g], 1.0f);
  float pv = pooled[g * 64 + c] * inv;
#pragma unroll
  for (int k = 0; k < 10; ++k) {
    float v = pv * lw[c * 10 + k];
#pragma unroll
    for (int o = 1; o < 64; o <<= 1) v += __shfl_xor(v, o);
    if (c == 0) out[g * 10 + k] = v + lb[k];
  }
}

extern "C" void kernel_launch(void* const* d_in, const int* in_sizes, int n_in,
                              void* d_out, int out_size, void* d_ws, size_t ws_size,
                              hipStream_t stream) {
  const float* x = (const float*)d_in[0];
  const int* ei = (const int*)d_in[1];
  const int* batch = (const int*)d_in[2];
  const float* W1 = (const float*)d_in[3];
  const float* as1 = (const float*)d_in[4];
  const float* ad1 = (const float*)d_in[5];
  const float* b1 = (const float*)d_in[6];
  const float* W2 = (const float*)d_in[7];
  const float* as2 = (const float*)d_in[8];
  const float* ad2 = (const float*)d_in[9];
  const float* b2 = (const float*)d_in[10];
  const float* lw = (const float*)d_in[11];
  const float* lb = (const float*)d_in[12];
  float* out = (float*)d_out;

  const int N = in_sizes[2];        // 50000
  const int E = in_sizes[1] / 2;    // 800000
  const int ET = E + N;             // + self loops
  const int F = in_sizes[0] / N;    // 128
  const int HC = in_sizes[6];       // 192
  const int LH = in_sizes[10];      // 64

  size_t off = 0;
  auto alo = [&](size_t bytes) -> char* {
    char* p = (char*)d_ws + off;
    off += (bytes + 255) & ~(size_t)255;
    return p;
  };
  int* cursor = (int*)alo((size_t)N * 4);
  float* pooled = (float*)alo((size_t)GRAPHS * 64 * 4);
  float* gcnt = (float*)alo((size_t)GRAPHS * 4);
  float* aS1 = (float*)alo((size_t)N * 4 * 4);      // stride-4 padded; atomic-accumulated
  float* aD1 = (float*)alo((size_t)N * 4 * 4);
  float* aS2 = (float*)alo((size_t)N * 4);
  float* aD2 = (float*)alo((size_t)N * 4);
  size_t zbytes = off;                              // zero everything above
  int* rowptr = (int*)alo(((size_t)N + 1) * 4);
  int* csrs = (int*)alo((size_t)ET * 4);
  int* bsum = (int*)alo(64 * 4);
  __half* xh = (__half*)alo((size_t)N * F * 2);
  __half* w1t = (__half*)alo((size_t)HC * F * 2);
  __half* w2t = (__half*)alo((size_t)LH * HC * 2);
  __half* xp1 = (__half*)alo((size_t)N * 192 * 2 + 512);  // +pad: DMA clamp overreach
  __half* h1 = (__half*)alo((size_t)N * 192 * 2 + 512);
  __half* xp2 = (__half*)alo((size_t)N * 64 * 2 + 512);

  hipMemsetAsync(d_ws, 0, zbytes, stream);
  int eb = (ET + 255) / 256;
  k_deg<<<eb, 256, 0, stream>>>(ei, E, ET, cursor);
  int nb = (N + 1023) / 1024;
  k_s1<<<nb, 256, 0, stream>>>(cursor, N, bsum);
  k_s2<<<1, 64, 0, stream>>>(bsum, nb);
  k_s3<<<nb, 256, 0, stream>>>(cursor, bsum, rowptr, N);
  k_scatter<<<eb, 256, 0, stream>>>(ei, E, ET, cursor, csrs);

  // fp16 inputs for MFMA
  int n4 = (N * F) / 4;
  k_cvtx<<<(n4 + 255) / 256, 256, 0, stream>>>(x, xh, n4);
  k_wt<<<(F * HC + 255) / 256, 256, 0, stream>>>(W1, w1t, F, HC);
  k_wt<<<(HC * LH + 255) / 256, 256, 0, stream>>>(W2, w2t, HC, LH);

  int mt = (N + 15) / 16;   // 3125
  int ab = (N + 3) / 4;

  // ---- layer 1: MFMA GEMM + agg (head-split) ----
  dim3 gm1(mt, HC / 64);    // grid.y*4 waves cover 12 n-tiles
  k_mfma<<<gm1, 256, 0, stream>>>(xh, w1t, xp1, as1, ad1, aS1, aD1, N, F, HC, 4);
  dim3 ga1(ab, 3);
  k_agg1<true, false><<<ga1, 256, 0, stream>>>(rowptr, csrs, xp1, aS1, aD1, b1, h1,
                                               nullptr, nullptr, nullptr, N, 4, 192, 192);
  // ---- layer 2: MFMA GEMM + agg (pooled) ----
  dim3 gm2(mt, LH / 64);
  k_mfma<<<gm2, 256, 0, stream>>>(h1, w2t, xp2, as2, ad2, aS2, aD2, N, HC, LH, 1);
  dim3 ga2(ab, 1);
  k_agg1<false, true><<<ga2, 256, 0, stream>>>(rowptr, csrs, xp2, aS2, aD2, b2, nullptr,
                                               batch, pooled, gcnt, N, 1, 64, 64);
  k_final<<<GRAPHS, 64, 0, stream>>>(pooled, gcnt, lw, lb, out);
}

// Round 15
// 601.341 us; speedup vs baseline: 1.1202x; 1.1202x over previous
//
#include <hip/hip_runtime.h>
#include <hip/hip_fp16.h>
#include <cstdint>

#define GRAPHS 128

using half8 = __attribute__((ext_vector_type(8))) _Float16;
using f32x4 = __attribute__((ext_vector_type(4))) float;

__device__ __forceinline__ float lane_bcast_f(float v, int l) {
  return __int_as_float(__builtin_amdgcn_readlane(__float_as_int(v), l));
}
__device__ __forceinline__ void load_lds16(const __half* g, __half* l) {
  __builtin_amdgcn_global_load_lds(
      (const __attribute__((address_space(1))) void*)g,
      (__attribute__((address_space(3))) void*)l, 16, 0, 0);
}
#define WAIT_VM0   __builtin_amdgcn_s_waitcnt(0x0F70)  // vmcnt(0) only
#define WAIT_LGKM0 __builtin_amdgcn_s_waitcnt(0xC07F)  // lgkmcnt(0) only

// ---------------- edge prep: degree -> scan -> scatter (CSR by dst) ----------------

__global__ __launch_bounds__(256) void k_deg(const int* __restrict__ ei, int E, int ET,
                                             int* __restrict__ deg) {
  int e = blockIdx.x * 256 + threadIdx.x;
  if (e >= ET) return;
  int d = (e < E) ? ei[E + e] : (e - E);
  atomicAdd(&deg[d], 1);
}

__global__ __launch_bounds__(256) void k_s1(const int* __restrict__ deg, int N,
                                            int* __restrict__ bsum) {
  int b = blockIdx.x, tid = threadIdx.x;
  int i0 = b * 1024 + tid * 4;
  int s = 0;
#pragma unroll
  for (int e = 0; e < 4; ++e) { int i = i0 + e; if (i < N) s += deg[i]; }
#pragma unroll
  for (int o = 32; o; o >>= 1) s += __shfl_xor(s, o);
  __shared__ int wt[4];
  int lane = tid & 63, wid = tid >> 6;
  if (lane == 0) wt[wid] = s;
  __syncthreads();
  if (tid == 0) bsum[b] = wt[0] + wt[1] + wt[2] + wt[3];
}

__global__ void k_s2(int* bsum, int nb) {
  if (threadIdx.x == 0) {
    int run = 0;
    for (int i = 0; i < nb; ++i) { int t = bsum[i]; bsum[i] = run; run += t; }
  }
}

__global__ __launch_bounds__(256) void k_s3(int* __restrict__ deg_cursor,
                                            const int* __restrict__ bsum,
                                            int* __restrict__ rowptr, int N) {
  int b = blockIdx.x, tid = threadIdx.x;
  int lane = tid & 63, wid = tid >> 6;
  int i0 = b * 1024 + tid * 4;
  int d[4];
#pragma unroll
  for (int e = 0; e < 4; ++e) { int i = i0 + e; d[e] = (i < N) ? deg_cursor[i] : 0; }
  int p0 = d[0], p1 = p0 + d[1], p2 = p1 + d[2], p3 = p2 + d[3];
  int incl = p3;
#pragma unroll
  for (int o = 1; o < 64; o <<= 1) { int u = __shfl_up(incl, o); if (lane >= o) incl += u; }
  __shared__ int wt[4];
  if (lane == 63) wt[wid] = incl;
  __syncthreads();
  int woff = 0;
  for (int w = 0; w < wid; ++w) woff += wt[w];
  int ex = bsum[b] + woff + incl - p3;
  int pre[4] = {0, p0, p1, p2};
#pragma unroll
  for (int e = 0; e < 4; ++e) {
    int i = i0 + e;
    if (i < N) { int st = ex + pre[e]; deg_cursor[i] = st; rowptr[i + 1] = st + d[e]; }
  }
  if (b == 0 && tid == 0) rowptr[0] = 0;
}

__global__ __launch_bounds__(256) void k_scatter(const int* __restrict__ ei, int E, int ET,
                                                 int* __restrict__ cursor,
                                                 int* __restrict__ csrs) {
  int e = blockIdx.x * 256 + threadIdx.x;
  if (e >= ET) return;
  int s, d;
  if (e < E) { s = ei[e]; d = ei[E + e]; } else { s = d = e - E; }
  int pos = atomicAdd(&cursor[d], 1);
  csrs[pos] = s;
}

// ---------------- fp16 conversion / weight transpose ----------------

__global__ __launch_bounds__(256) void k_cvtx(const float* __restrict__ x,
                                              __half* __restrict__ xh, int n4) {
  int i = blockIdx.x * 256 + threadIdx.x;
  if (i >= n4) return;
  float4 v = *(const float4*)&x[(size_t)i * 4];
  __half2 a = __floats2half2_rn(v.x, v.y), b = __floats2half2_rn(v.z, v.w);
  *(__half2*)&xh[(size_t)i * 4] = a;
  *(__half2*)&xh[(size_t)i * 4 + 2] = b;
}

__global__ __launch_bounds__(256) void k_wt(const float* __restrict__ W,
                                            __half* __restrict__ Wt, int K, int NC) {
  int id = blockIdx.x * 256 + threadIdx.x;
  if (id >= K * NC) return;
  int nn = id / K, kk = id % K;
  Wt[(size_t)nn * K + kk] = __float2half(W[(size_t)kk * NC + nn]);
}

// ---------------- MFMA GEMM, LDS-tiled (64x64 per block), fused attention dots --------------
// Wave w: n-slice [nblk+w*16, +16). A-tile staged in LDS (4x reuse); B-frags in regs (4x
// reuse over m-subtiles). Frag maps verified R14: A[m=lane&15][k=quad*8+j] from row-major;
// B same from Bt[n][k]; C/D col=lane&15,row=quad*4+r. att dots: LDS partials, direct store.

template <int KT, int ASTR>
__global__ __launch_bounds__(256) void k_gemm_mfma(
    const __half* __restrict__ Ah, const __half* __restrict__ Bth,
    __half* __restrict__ C, const float* __restrict__ attS, const float* __restrict__ attD,
    float* __restrict__ aS, float* __restrict__ aD, int M, int NC) {
  constexpr int K8 = KT / 8;
  constexpr int KS = KT / 32;
  __shared__ __align__(16) _Float16 Asm[64 * KT];
  __shared__ float sS[64][4], sD[64][4];
  int tid = threadIdx.x;
  int w = tid >> 6, lane = tid & 63;
  int col = lane & 15, quad = lane >> 4;
  int m0 = blockIdx.x * 64;
  int nblk = blockIdx.y * 64;
  int head = blockIdx.y;
  // ---- stage A tile (coalesced half8) ----
  const half8* A8 = (const half8*)Ah;
  half8* As8 = (half8*)Asm;
  for (int i = tid; i < 64 * K8; i += 256) {
    int row = i / K8, c8 = i % K8;
    int gm = min(m0 + row, M - 1);
    As8[i] = A8[(size_t)gm * K8 + c8];
  }
  __syncthreads();
  // ---- B frags preloaded ----
  int n0w = nblk + w * 16;
  const half8* B8 = (const half8*)Bth;
  half8 bf[KS];
#pragma unroll
  for (int s = 0; s < KS; ++s) bf[s] = B8[(size_t)(n0w + col) * K8 + s * 4 + quad];
  float asv = attS[n0w + col], adv = attD[n0w + col];
  f32x4 accs[4];
#pragma unroll
  for (int i = 0; i < 4; ++i) {
    f32x4 acc = {0.f, 0.f, 0.f, 0.f};
#pragma unroll
    for (int s = 0; s < KS; ++s) {
      half8 a = *(const half8*)&Asm[(i * 16 + col) * KT + s * 32 + quad * 8];
      acc = __builtin_amdgcn_mfma_f32_16x16x32_f16(a, bf[s], acc, 0, 0, 0);
    }
    accs[i] = acc;
#pragma unroll
    for (int r = 0; r < 4; ++r) {
      float sv = acc[r] * asv, dv = acc[r] * adv;
#pragma unroll
      for (int o = 1; o < 16; o <<= 1) { sv += __shfl_xor(sv, o); dv += __shfl_xor(dv, o); }
      if (col == 0) {
        int ml = i * 16 + quad * 4 + r;
        sS[ml][w] = sv; sD[ml][w] = dv;
      }
    }
  }
  __syncthreads();   // Asm reads + sS/sD writes complete
  // ---- att dots: direct store (no atomics) ----
  if (tid < 64) {
    int m = m0 + tid;
    if (m < M) {
      aS[(size_t)m * ASTR + head] = sS[tid][0] + sS[tid][1] + sS[tid][2] + sS[tid][3];
      aD[(size_t)m * ASTR + head] = sD[tid][0] + sD[tid][1] + sD[tid][2] + sD[tid][3];
    }
  }
  // ---- C via LDS transpose -> coalesced half8 stores ----
  _Float16* Cs = Asm;  // reuse (8KB <= tile)
#pragma unroll
  for (int i = 0; i < 4; ++i)
#pragma unroll
    for (int r = 0; r < 4; ++r)
      Cs[(i * 16 + quad * 4 + r) * 64 + w * 16 + col] = (_Float16)accs[i][r];
  __syncthreads();
  for (int i = tid; i < 64 * 8; i += 256) {
    int row = i >> 3, c8 = i & 7;
    int gm = m0 + row;
    if (gm < M)
      *(half8*)&C[(size_t)gm * NC + nblk + c8 * 8] = ((half8*)Cs)[row * 8 + c8];
  }
}

// ---------------- single-head wave-per-(node,head) softmax + wide-DMA fp16 aggregation -------

template <bool DOELU, bool POOL>
__global__ __launch_bounds__(256) void k_agg1(
    const int* __restrict__ rowptr, const int* __restrict__ csrs,
    const __half* __restrict__ xp, const float* __restrict__ aS, const float* __restrict__ aD,
    const float* __restrict__ bias, __half* __restrict__ out,
    const int* __restrict__ batch, float* __restrict__ pooled, float* __restrict__ gcnt,
    int N, int astr, int rowstr, int outstr) {
  __shared__ __half stage[4][1024];
  int wv = (blockIdx.x * blockDim.x + threadIdx.x) >> 6;
  int lane = threadIdx.x & 63;
  int wid = (threadIdx.x >> 6) & 3;
  if (wv >= N) return;
  __half* st = stage[wid];
  int head = blockIdx.y;
  int coloff = head * 64;
  int n = wv;
  int start = rowptr[n], end = rowptr[n + 1];
  float ad = aD[(size_t)n * astr + head];
  float m = -1e30f, s = 0.f, al = 0.f, cf = 0.f, acc = 0.f;
  int myS = -1;
  int j = start + lane;
  if (j < end) {
    myS = csrs[j];
    float v = aS[(size_t)myS * astr + head] + ad;
    v = v > 0.f ? v : 0.2f * v;
    al = v; m = v; s = 1.f;
  }
  for (int jj = j + 64; jj < end; jj += 64) {  // degree > 64 (rare)
    int sb = csrs[jj];
    float v = aS[(size_t)sb * astr + head] + ad;
    v = v > 0.f ? v : 0.2f * v;
    float M = fmaxf(m, v);
    s = s * __expf(m - M) + __expf(v - M);
    m = M;
  }
  {
    float mm = m, ss = s;
#pragma unroll
    for (int o = 1; o < 64; o <<= 1) {
      float om = __shfl_xor(mm, o), os = __shfl_xor(ss, o);
      float M = fmaxf(mm, om);
      ss = ss * __expf(mm - M) + os * __expf(om - M);
      mm = M;
    }
    m = mm;
    s = 1.0f / fmaxf(ss, 1e-16f);
  }
  if (myS >= 0) cf = __expf(al - m) * s;
  for (int base = start; base < end; base += 64) {
    int cnt = min(64, end - base);
    int sreg; float dd;
    if (base == start) {
      sreg = myS; dd = cf;
    } else {  // degree > 64 spillover (rare)
      int jj = base + lane; sreg = 0; dd = 0.f;
      if (jj < end) {
        sreg = csrs[jj];
        float v = aS[(size_t)sreg * astr + head] + ad;
        v = v > 0.f ? v : 0.2f * v;
        dd = __expf(v - m) * s;
      }
    }
    for (int e = 0; e < cnt; e += 16) {
      WAIT_LGKM0;
#pragma unroll
      for (int k = 0; k < 2; ++k) {
        int ee = min(e + 8 * k + (lane >> 3), cnt - 1);
        int sb = __shfl(sreg, ee);
        const __half* g = xp + (size_t)sb * rowstr + coloff + (lane & 7) * 8;
        load_lds16(g, st + k * 512);
      }
      WAIT_VM0;
#pragma unroll
      for (int u = 0; u < 16; ++u) {
        float c = (e + u < cnt) ? lane_bcast_f(dd, e + u) : 0.f;
        acc = fmaf(c, __half2float(st[(u >> 3) * 512 + (u & 7) * 64 + lane]), acc);
      }
    }
  }
  if (POOL) {
    float val = acc + bias[lane];
    int g = batch[n];
    atomicAdd(&pooled[g * 64 + lane], val);
    if (lane == 0) atomicAdd(&gcnt[g], 1.0f);
  } else {
    float v = acc + bias[coloff + lane];
    if (DOELU) v = v > 0.f ? v : __expf(v) - 1.0f;
    out[(size_t)n * outstr + coloff + lane] = __float2half(v);
  }
}

// ---------------- final: mean + linear ----------------

__global__ __launch_bounds__(64) void k_final(const float* __restrict__ pooled,
                                              const float* __restrict__ gcnt,
                                              const float* __restrict__ lw,
                                              const float* __restrict__ lb,
                                              float* __restrict__ out) {
  int g = blockIdx.x, c = threadIdx.x;
  float inv = 1.0f / fmaxf(gcnt[g], 1.0f);
  float pv = pooled[g * 64 + c] * inv;
#pragma unroll
  for (int k = 0; k < 10; ++k) {
    float v = pv * lw[c * 10 + k];
#pragma unroll
    for (int o = 1; o < 64; o <<= 1) v += __shfl_xor(v, o);
    if (c == 0) out[g * 10 + k] = v + lb[k];
  }
}

extern "C" void kernel_launch(void* const* d_in, const int* in_sizes, int n_in,
                              void* d_out, int out_size, void* d_ws, size_t ws_size,
                              hipStream_t stream) {
  const float* x = (const float*)d_in[0];
  const int* ei = (const int*)d_in[1];
  const int* batch = (const int*)d_in[2];
  const float* W1 = (const float*)d_in[3];
  const float* as1 = (const float*)d_in[4];
  const float* ad1 = (const float*)d_in[5];
  const float* b1 = (const float*)d_in[6];
  const float* W2 = (const float*)d_in[7];
  const float* as2 = (const float*)d_in[8];
  const float* ad2 = (const float*)d_in[9];
  const float* b2 = (const float*)d_in[10];
  const float* lw = (const float*)d_in[11];
  const float* lb = (const float*)d_in[12];
  float* out = (float*)d_out;

  const int N = in_sizes[2];        // 50000
  const int E = in_sizes[1] / 2;    // 800000
  const int ET = E + N;             // + self loops
  const int F = in_sizes[0] / N;    // 128
  const int HC = in_sizes[6];       // 192
  const int LH = in_sizes[10];      // 64

  size_t off = 0;
  auto alo = [&](size_t bytes) -> char* {
    char* p = (char*)d_ws + off;
    off += (bytes + 255) & ~(size_t)255;
    return p;
  };
  int* cursor = (int*)alo((size_t)N * 4);
  float* pooled = (float*)alo((size_t)GRAPHS * 64 * 4);
  float* gcnt = (float*)alo((size_t)GRAPHS * 4);
  size_t zbytes = off;                              // zero everything above
  float* aS1 = (float*)alo((size_t)N * 4 * 4);      // stride-4; direct-stored by GEMM
  float* aD1 = (float*)alo((size_t)N * 4 * 4);
  float* aS2 = (float*)alo((size_t)N * 4);
  float* aD2 = (float*)alo((size_t)N * 4);
  int* rowptr = (int*)alo(((size_t)N + 1) * 4);
  int* csrs = (int*)alo((size_t)ET * 4);
  int* bsum = (int*)alo(64 * 4);
  __half* xh = (__half*)alo((size_t)N * F * 2);
  __half* w1t = (__half*)alo((size_t)HC * F * 2);
  __half* w2t = (__half*)alo((size_t)LH * HC * 2);
  __half* xp1 = (__half*)alo((size_t)N * 192 * 2 + 512);  // +pad: DMA clamp overreach
  __half* h1 = (__half*)alo((size_t)N * 192 * 2 + 512);
  __half* xp2 = (__half*)alo((size_t)N * 64 * 2 + 512);

  hipMemsetAsync(d_ws, 0, zbytes, stream);
  int eb = (ET + 255) / 256;
  k_deg<<<eb, 256, 0, stream>>>(ei, E, ET, cursor);
  int nb = (N + 1023) / 1024;
  k_s1<<<nb, 256, 0, stream>>>(cursor, N, bsum);
  k_s2<<<1, 64, 0, stream>>>(bsum, nb);
  k_s3<<<nb, 256, 0, stream>>>(cursor, bsum, rowptr, N);
  k_scatter<<<eb, 256, 0, stream>>>(ei, E, ET, cursor, csrs);

  // fp16 inputs for MFMA
  int n4 = (N * F) / 4;
  k_cvtx<<<(n4 + 255) / 256, 256, 0, stream>>>(x, xh, n4);
  k_wt<<<(F * HC + 255) / 256, 256, 0, stream>>>(W1, w1t, F, HC);
  k_wt<<<(HC * LH + 255) / 256, 256, 0, stream>>>(W2, w2t, HC, LH);

  int mb = (N + 63) / 64;   // 782
  int ab = (N + 3) / 4;

  // ---- layer 1: MFMA GEMM (LDS-tiled) + agg (head-split) ----
  dim3 gm1(mb, HC / 64);
  k_gemm_mfma<128, 4><<<gm1, 256, 0, stream>>>(xh, w1t, xp1, as1, ad1, aS1, aD1, N, HC);
  dim3 ga1(ab, 3);
  k_agg1<true, false><<<ga1, 256, 0, stream>>>(rowptr, csrs, xp1, aS1, aD1, b1, h1,
                                               nullptr, nullptr, nullptr, N, 4, 192, 192);
  // ---- layer 2: MFMA GEMM + agg (pooled) ----
  dim3 gm2(mb, LH / 64);
  k_gemm_mfma<192, 1><<<gm2, 256, 0, stream>>>(h1, w2t, xp2, as2, ad2, aS2, aD2, N, LH);
  dim3 ga2(ab, 1);
  k_agg1<false, true><<<ga2, 256, 0, stream>>>(rowptr, csrs, xp2, aS2, aD2, b2, nullptr,
                                               batch, pooled, gcnt, N, 1, 64, 64);
  k_final<<<GRAPHS, 64, 0, stream>>>(pooled, gcnt, lw, lb, out);
}